// Round 1
// baseline (3116.751 us; speedup 1.0000x reference)
//
#include <hip/hip_runtime.h>
#include <cstdint>
#include <cstddef>

// Problem constants (match reference: B=64, L=512, STEPS=20)
#define LDIM 512
#define BATCH 64
#define NSTEPS 20
#define NTHREADS 256
#define PTHREADS 1024

using f4 = __attribute__((ext_vector_type(4))) float;

__device__ __forceinline__ float relu_f(float x) { return fmaxf(x, 0.0f); }
__device__ __forceinline__ float sign_f(float x) {
  return (x > 0.0f) ? 1.0f : ((x < 0.0f) ? -1.0f : 0.0f);
}
__device__ __forceinline__ float wave_reduce_sum(float v) {
  v += __shfl_xor(v, 32);
  v += __shfl_xor(v, 16);
  v += __shfl_xor(v, 8);
  v += __shfl_xor(v, 4);
  v += __shfl_xor(v, 2);
  v += __shfl_xor(v, 1);
  return v;
}
// agent-scope (device) accesses for cross-block partial exchange
__device__ __forceinline__ void st_agent(float* p, float v) {
  __hip_atomic_store(p, v, __ATOMIC_RELAXED, __HIP_MEMORY_SCOPE_AGENT);
}
__device__ __forceinline__ float ld_agent(const float* p) {
  return __hip_atomic_load(p, __ATOMIC_RELAXED, __HIP_MEMORY_SCOPE_AGENT);
}

// ---------------------------------------------------------------------------
// k_build: MU[b][i][j] = M_ij ? 0.5*(sc_ij + sc_ji) - s : -1e30, via 64x64
// tile pairs (coalesced transpose through LDS — kills k_init's 4.4x overfetch).
// Also zeroes the per-batch sync counters for the persistent kernel.
// Grid: BATCH * 36 tile pairs; 256 threads.
// ---------------------------------------------------------------------------
__global__ __launch_bounds__(NTHREADS) void k_build(
    const float* __restrict__ scores, const float* __restrict__ M,
    const float* __restrict__ s_ptr, float* __restrict__ MU,
    unsigned int* __restrict__ counter) {
  __shared__ float Sa[64][65];
  __shared__ float Sb[64][65];
  if (blockIdx.x < BATCH && threadIdx.x == 0) counter[blockIdx.x] = 0u;
  const int b = blockIdx.x / 36;
  int rem = blockIdx.x % 36;
  int ti = 0;
  while (rem >= 8 - ti) {
    rem -= 8 - ti;
    ti++;
  }
  const int tj = ti + rem;
  const int tid = threadIdx.x;
  const int c = tid & 63;
  const int r0 = tid >> 6;
  const float sval = s_ptr[0];
  const size_t mb = (size_t)b * LDIM * LDIM;
#pragma unroll
  for (int k = 0; k < 16; k++) {
    const int r = 4 * k + r0;
    Sa[r][c] = scores[mb + (size_t)(ti * 64 + r) * LDIM + tj * 64 + c];
    Sb[r][c] = scores[mb + (size_t)(tj * 64 + r) * LDIM + ti * 64 + c];
  }
  __syncthreads();
#pragma unroll
  for (int k = 0; k < 16; k++) {
    const int r = 4 * k + r0;
    const size_t idx_ij = mb + (size_t)(ti * 64 + r) * LDIM + tj * 64 + c;
    const float mij = M[idx_ij];
    const float us = 0.5f * (Sa[r][c] + Sb[c][r]) - sval;
    MU[idx_ij] = (mij != 0.0f) ? us : -1e30f;
    if (ti != tj) {
      const size_t idx_ji = mb + (size_t)(tj * 64 + r) * LDIM + ti * 64 + c;
      const float mji = M[idx_ji];
      const float usj = 0.5f * (Sb[r][c] + Sa[c][r]) - sval;
      MU[idx_ji] = (mji != 0.0f) ? usj : -1e30f;
    }
  }
}

// ---------------------------------------------------------------------------
// k_persist: all 20 steps with A_hat resident on-chip.
// Grid 256 blocks x 1024 threads, 1 block/CU. Block (b = blockIdx&63,
// sb = blockIdx>>6) owns rows [sb*128, sb*128+128) of batch b.
// Per wave (16 waves): 8 rows; rows 0..3 live in VGPRs (f4 ahv[4][2]),
// rows 4..7 in LDS ahL (64 rows x 512 = 128 KB). Lane l covers cols
// [4l..4l+3] and [256+4l..256+4l+3].
// Per step, blocks of a batch exchange only row/col partial sums (2.5 KB)
// through agent-scope stores + a monotonic per-batch arrival counter.
// ---------------------------------------------------------------------------
__global__ __launch_bounds__(PTHREADS, 4) void k_persist(
    const float* __restrict__ scores, const float* __restrict__ MU,
    const float* __restrict__ rho_p, const float* __restrict__ w_ptr,
    const float* __restrict__ alpha_ptr, const float* __restrict__ belt_ptr,
    const float* __restrict__ lra_ptr, const float* __restrict__ lrb_ptr,
    float* __restrict__ rowpart, float* __restrict__ colpart,
    unsigned int* __restrict__ counter, float* __restrict__ Ah) {
  __shared__ float ahL[64][LDIM];    // 128 KB: LDS-resident half of A_hat slab
  __shared__ float stage[8][LDIM];   // 16 KB: cross-wave col-sum staging
  __shared__ float lmsgS[LDIM];      // 2 KB
  __shared__ float LmS[LDIM];        // 2 KB   (total 148 KB <= 160 KB)

  const int tid = threadIdx.x;
  const int lane = tid & 63;
  const int w = tid >> 6;
  const int b = blockIdx.x & (BATCH - 1);  // blocks of a batch share an XCD
  const int sb = blockIdx.x >> 6;          // slab 0..3
  const int wrow = sb * 128 + w * 8;
  const int j0 = lane << 2;
  const size_t mb = (size_t)b * LDIM * LDIM;

  const float wv = w_ptr[0];
  const float belt = belt_ptr[0];
  const float lra = lra_ptr[0];
  const float lrb = lrb_ptr[0];
  float at = alpha_ptr[0];  // a_t = alpha * lra^sp, updated iteratively
  float lrbp = 1.0f;        // lrb^(sp-1) for sp>=1

  const size_t RP = (size_t)BATCH * LDIM;      // rowpart buffer stride (parity)
  const size_t CP = (size_t)BATCH * 4 * LDIM;  // colpart buffer stride (parity)
  unsigned int* const cnt = counter + b;

  f4 ahv[4][2];
  float colacc[8];

#define ARRIVE_WAIT(tgt)                                                       \
  do {                                                                         \
    __threadfence();                                                           \
    __syncthreads();                                                           \
    if (tid == 0) {                                                            \
      __hip_atomic_fetch_add(cnt, 1u, __ATOMIC_RELEASE,                        \
                             __HIP_MEMORY_SCOPE_AGENT);                        \
      while (__hip_atomic_load(cnt, __ATOMIC_ACQUIRE,                          \
                               __HIP_MEMORY_SCOPE_AGENT) < (tgt))              \
        __builtin_amdgcn_s_sleep(8);                                           \
    }                                                                          \
    __syncthreads();                                                           \
  } while (0)

#define COLREDUCE_STORE(dstp)                                                  \
  do {                                                                         \
    if (w < 8) {                                                               \
      f4 sa = {colacc[0], colacc[1], colacc[2], colacc[3]};                    \
      f4 sbv = {colacc[4], colacc[5], colacc[6], colacc[7]};                   \
      *(f4*)&stage[w][j0] = sa;                                                \
      *(f4*)&stage[w][256 + j0] = sbv;                                         \
    }                                                                          \
    __syncthreads();                                                           \
    if (w >= 8) {                                                              \
      f4 sa = *(f4*)&stage[w - 8][j0];                                         \
      f4 sbv = *(f4*)&stage[w - 8][256 + j0];                                  \
      sa[0] += colacc[0]; sa[1] += colacc[1];                                  \
      sa[2] += colacc[2]; sa[3] += colacc[3];                                  \
      sbv[0] += colacc[4]; sbv[1] += colacc[5];                                \
      sbv[2] += colacc[6]; sbv[3] += colacc[7];                                \
      *(f4*)&stage[w - 8][j0] = sa;                                            \
      *(f4*)&stage[w - 8][256 + j0] = sbv;                                     \
    }                                                                          \
    __syncthreads();                                                           \
    if (tid < LDIM) {                                                          \
      float cs = stage[0][tid] + stage[1][tid] + stage[2][tid] +               \
                 stage[3][tid] + stage[4][tid] + stage[5][tid] +               \
                 stage[6][tid] + stage[7][tid];                                \
      st_agent((dstp) + tid, cs);                                              \
    }                                                                          \
  } while (0)

  // ---- P_init: A_hat_0 = scores into regs/LDS; partials of M .* A_hat_0 ----
#pragma unroll
  for (int k = 0; k < 8; k++) colacc[k] = 0.0f;
#pragma unroll
  for (int r = 0; r < 8; r++) {
    const int i = wrow + r;
    const size_t base = mb + (size_t)i * LDIM;
    const f4 s0 = *(const f4*)(scores + base + j0);
    const f4 s1 = *(const f4*)(scores + base + 256 + j0);
    const f4 m0 = *(const f4*)(MU + base + j0);
    const f4 m1 = *(const f4*)(MU + base + 256 + j0);
    if (r < 4) {
      ahv[r][0] = s0;
      ahv[r][1] = s1;
    } else {
      *(f4*)&ahL[(w << 2) + (r - 4)][j0] = s0;
      *(f4*)&ahL[(w << 2) + (r - 4)][256 + j0] = s1;
    }
    float rowc = 0.0f;
#pragma unroll
    for (int k = 0; k < 4; k++) {
      const float c0v = (m0[k] > -1e29f) ? s0[k] : 0.0f;
      const float c1v = (m1[k] > -1e29f) ? s1[k] : 0.0f;
      rowc += c0v + c1v;
      colacc[k] += c0v;
      colacc[4 + k] += c1v;
    }
    const float rsum = wave_reduce_sum(rowc);
    if (lane == 0) st_agent(rowpart + (size_t)b * LDIM + i, rsum);
  }
  COLREDUCE_STORE(colpart + ((size_t)b * 4 + sb) * LDIM);
  ARRIVE_WAIT(4u);

  // ---- 20 steps ----
  for (int sp = 0; sp < NSTEPS; ++sp) {
    const int par = sp & 1;
    // lm phase: identical on all 4 sibling blocks (bit-deterministic).
    if (tid < LDIM) {
      const int i = tid;
      const float rsum = ld_agent(rowpart + (size_t)par * RP + (size_t)b * LDIM + i);
      const float* cb = colpart + (size_t)par * CP + (size_t)b * 4 * LDIM + i;
      const float csum = ld_agent(cb) + ld_agent(cb + LDIM) +
                         ld_agent(cb + 2 * LDIM) + ld_agent(cb + 3 * LDIM);
      const float rd = 0.5f * (rsum + csum) - 1.0f;
      float lm;
      if (sp == 0)
        lm = wv * relu_f(rd);
      else
        lm = LmS[i] + belt * lrbp * relu_f(rd);
      LmS[i] = lm;
      lmsgS[i] = lm * sign_f(rd);
    }
    __syncthreads();

    const f4 lmja = *(const f4*)&lmsgS[j0];
    const f4 lmjb = *(const f4*)&lmsgS[256 + j0];
    const bool last = (sp == NSTEPS - 1);
    const float rat = at;
#pragma unroll
    for (int k = 0; k < 8; k++) colacc[k] = 0.0f;

    // VGPR-resident rows
#pragma unroll
    for (int r = 0; r < 4; r++) {
      const int i = wrow + r;
      const size_t base = mb + (size_t)i * LDIM;
      const float lmi = lmsgS[i];
      const f4 mu0 = *(const f4*)(MU + base + j0);
      const f4 mu1 = *(const f4*)(MU + base + 256 + j0);
      const f4 rh0 = *(const f4*)(rho_p + (size_t)i * LDIM + j0);
      const f4 rh1 = *(const f4*)(rho_p + (size_t)i * LDIM + 256 + j0);
      float rowc = 0.0f;
#pragma unroll
      for (int k = 0; k < 4; k++) {
        const bool ma = mu0[k] > -1e29f;
        const float ga = ma ? (mu0[k] - lmi - lmja[k]) : 0.0f;
        const float ua = ahv[r][0][k] * fmaf(rat, ga, 1.0f);
        const float va = fminf(relu_f(fabsf(ua) - rh0[k] * rat), 1.0f);
        ahv[r][0][k] = va;
        const float ca = ma ? va : 0.0f;
        rowc += ca;
        colacc[k] += ca;
        const bool mbk = mu1[k] > -1e29f;
        const float gb = mbk ? (mu1[k] - lmi - lmjb[k]) : 0.0f;
        const float ub = ahv[r][1][k] * fmaf(rat, gb, 1.0f);
        const float vb = fminf(relu_f(fabsf(ub) - rh1[k] * rat), 1.0f);
        ahv[r][1][k] = vb;
        const float cbv = mbk ? vb : 0.0f;
        rowc += cbv;
        colacc[4 + k] += cbv;
      }
      if (!last) {
        const float rsum = wave_reduce_sum(rowc);
        if (lane == 0)
          st_agent(rowpart + (size_t)(par ^ 1) * RP + (size_t)b * LDIM + i, rsum);
      }
    }
    // LDS-resident rows
#pragma unroll 2
    for (int r = 4; r < 8; r++) {
      const int i = wrow + r;
      const size_t base = mb + (size_t)i * LDIM;
      const int lr = (w << 2) + (r - 4);
      const float lmi = lmsgS[i];
      const f4 mu0 = *(const f4*)(MU + base + j0);
      const f4 mu1 = *(const f4*)(MU + base + 256 + j0);
      const f4 rh0 = *(const f4*)(rho_p + (size_t)i * LDIM + j0);
      const f4 rh1 = *(const f4*)(rho_p + (size_t)i * LDIM + 256 + j0);
      f4 a0 = *(const f4*)&ahL[lr][j0];
      f4 a1 = *(const f4*)&ahL[lr][256 + j0];
      float rowc = 0.0f;
#pragma unroll
      for (int k = 0; k < 4; k++) {
        const bool ma = mu0[k] > -1e29f;
        const float ga = ma ? (mu0[k] - lmi - lmja[k]) : 0.0f;
        const float ua = a0[k] * fmaf(rat, ga, 1.0f);
        const float va = fminf(relu_f(fabsf(ua) - rh0[k] * rat), 1.0f);
        a0[k] = va;
        const float ca = ma ? va : 0.0f;
        rowc += ca;
        colacc[k] += ca;
        const bool mbk = mu1[k] > -1e29f;
        const float gb = mbk ? (mu1[k] - lmi - lmjb[k]) : 0.0f;
        const float ub = a1[k] * fmaf(rat, gb, 1.0f);
        const float vb = fminf(relu_f(fabsf(ub) - rh1[k] * rat), 1.0f);
        a1[k] = vb;
        const float cbv = mbk ? vb : 0.0f;
        rowc += cbv;
        colacc[4 + k] += cbv;
      }
      *(f4*)&ahL[lr][j0] = a0;
      *(f4*)&ahL[lr][256 + j0] = a1;
      if (!last) {
        const float rsum = wave_reduce_sum(rowc);
        if (lane == 0)
          st_agent(rowpart + (size_t)(par ^ 1) * RP + (size_t)b * LDIM + i, rsum);
      }
    }
    if (!last) {
      COLREDUCE_STORE(colpart + (size_t)(par ^ 1) * CP + ((size_t)b * 4 + sb) * LDIM);
      ARRIVE_WAIT(4u * (unsigned)(sp + 2));
    }
    at *= lra;
    if (sp > 0) lrbp *= lrb;
  }

  // ---- write A_hat_20 out (k_final symmetrizes in place) ----
#pragma unroll
  for (int r = 0; r < 4; r++) {
    const size_t base = mb + (size_t)(wrow + r) * LDIM;
    *(f4*)(Ah + base + j0) = ahv[r][0];
    *(f4*)(Ah + base + 256 + j0) = ahv[r][1];
  }
#pragma unroll
  for (int r = 4; r < 8; r++) {
    const size_t base = mb + (size_t)(wrow + r) * LDIM;
    const int lr = (w << 2) + (r - 4);
    *(f4*)(Ah + base + j0) = *(const f4*)&ahL[lr][j0];
    *(f4*)(Ah + base + 256 + j0) = *(const f4*)&ahL[lr][256 + j0];
  }
#undef ARRIVE_WAIT
#undef COLREDUCE_STORE
}

// ---------------------------------------------------------------------------
// K_final: in-place A = 0.5*(Ah + Ah^T) .* M over tile pairs (64x64 tiles).
// ---------------------------------------------------------------------------
__global__ __launch_bounds__(NTHREADS) void k_final(float* __restrict__ Ah,
                                                    const float* __restrict__ M) {
  __shared__ float At[64][65];
  __shared__ float Bt[64][65];
  const int b = blockIdx.x / 36;
  int rem = blockIdx.x % 36;
  int ti = 0;
  while (rem >= 8 - ti) {
    rem -= 8 - ti;
    ti++;
  }
  const int tj = ti + rem;
  const int tid = threadIdx.x;
  const int c = tid & 63;
  const int r0 = tid >> 6;
  const size_t mb = (size_t)b * LDIM * LDIM;

#pragma unroll
  for (int k = 0; k < 16; k++) {
    const int r = 4 * k + r0;
    At[r][c] = Ah[mb + (size_t)(ti * 64 + r) * LDIM + tj * 64 + c];
    Bt[r][c] = Ah[mb + (size_t)(tj * 64 + r) * LDIM + ti * 64 + c];
  }
  __syncthreads();
#pragma unroll
  for (int k = 0; k < 16; k++) {
    const int r = 4 * k + r0;
    const size_t idx_ij = mb + (size_t)(ti * 64 + r) * LDIM + tj * 64 + c;
    const float mij = M[idx_ij];
    Ah[idx_ij] = 0.5f * (At[r][c] + Bt[c][r]) * mij;
    if (ti != tj) {
      const size_t idx_ji = mb + (size_t)(tj * 64 + r) * LDIM + ti * 64 + c;
      const float mji = M[idx_ji];
      Ah[idx_ji] = 0.5f * (Bt[r][c] + At[c][r]) * mji;
    }
  }
}

// ---------------------------------------------------------------------------
extern "C" void kernel_launch(void* const* d_in, const int* in_sizes, int n_in,
                              void* d_out, int out_size, void* d_ws,
                              size_t ws_size, hipStream_t stream) {
  const float* scores = (const float*)d_in[0];
  const float* M = (const float*)d_in[1];
  const float* s_p = (const float*)d_in[2];
  const float* w_p = (const float*)d_in[3];
  const float* rho = (const float*)d_in[4];
  const float* alpha_p = (const float*)d_in[5];
  const float* belt_p = (const float*)d_in[6];
  const float* lra_p = (const float*)d_in[7];
  const float* lrb_p = (const float*)d_in[8];
  float* Ah = (float*)d_out;

  char* ws = (char*)d_ws;
  size_t off = 0;
  auto walloc = [&](size_t bytes) -> void* {
    void* p = (void*)(ws + off);
    off += (bytes + 255) & ~(size_t)255;
    return p;
  };
  const size_t NEL = (size_t)BATCH * LDIM * LDIM;
  float* MU = (float*)walloc(NEL * 4);                              // 64 MB
  float* rowpart = (float*)walloc((size_t)2 * BATCH * LDIM * 4);    // 256 KB
  float* colpart = (float*)walloc((size_t)2 * BATCH * 4 * LDIM * 4);// 1 MB
  unsigned int* cnt = (unsigned int*)walloc(BATCH * 4);             // 256 B
  (void)in_sizes;
  (void)n_in;
  (void)out_size;
  (void)ws_size;

  k_build<<<dim3(BATCH * 36), dim3(NTHREADS), 0, stream>>>(scores, M, s_p, MU,
                                                           cnt);

  void* args[] = {(void*)&scores, (void*)&MU,      (void*)&rho,
                  (void*)&w_p,    (void*)&alpha_p, (void*)&belt_p,
                  (void*)&lra_p,  (void*)&lrb_p,   (void*)&rowpart,
                  (void*)&colpart, (void*)&cnt,    (void*)&Ah};
  hipError_t cerr = hipLaunchCooperativeKernel(
      (const void*)k_persist, dim3(BATCH * 4), dim3(PTHREADS), args, 0, stream);
  if (cerr != hipSuccess) {
    // Fallback: plain launch. 256 blocks at 1 block/CU on a 256-CU chip are
    // trivially co-resident; the per-batch counter sync is unchanged.
    k_persist<<<dim3(BATCH * 4), dim3(PTHREADS), 0, stream>>>(
        scores, MU, rho, w_p, alpha_p, belt_p, lra_p, lrb_p, rowpart, colpart,
        cnt, Ah);
  }

  k_final<<<dim3(BATCH * 36), dim3(NTHREADS), 0, stream>>>(Ah, M);
}

// Round 2
// 794.069 us; speedup vs baseline: 3.9250x; 3.9250x over previous
//
#include <hip/hip_runtime.h>
#include <cstdint>
#include <cstddef>

// Problem constants (match reference: B=64, L=512, STEPS=20)
#define LDIM 512
#define BATCH 64
#define NSTEPS 20
#define NTHREADS 256
#define PTHREADS 1024
#define CNT_STRIDE 16  // 64 B per counter: no atomic line sharing across batches

using f4 = __attribute__((ext_vector_type(4))) float;

__device__ __forceinline__ float relu_f(float x) { return fmaxf(x, 0.0f); }
__device__ __forceinline__ float sign_f(float x) {
  return (x > 0.0f) ? 1.0f : ((x < 0.0f) ? -1.0f : 0.0f);
}
__device__ __forceinline__ float wave_reduce_sum(float v) {
  v += __shfl_xor(v, 32);
  v += __shfl_xor(v, 16);
  v += __shfl_xor(v, 8);
  v += __shfl_xor(v, 4);
  v += __shfl_xor(v, 2);
  v += __shfl_xor(v, 1);
  return v;
}
// Agent-scope RELAXED accesses: compile to sc1 (L1/L2-bypassing) ops that are
// serviced at the coherence point (MALL). Never use acquire/threadfence here:
// agent-acquire emits buffer_inv (full per-XCD L2 invalidate) — the round-1
// kernel spent 97% of its time in exactly that.
__device__ __forceinline__ void st_agent(float* p, float v) {
  __hip_atomic_store(p, v, __ATOMIC_RELAXED, __HIP_MEMORY_SCOPE_AGENT);
}
__device__ __forceinline__ float ld_agent(const float* p) {
  return __hip_atomic_load(p, __ATOMIC_RELAXED, __HIP_MEMORY_SCOPE_AGENT);
}

// ---------------------------------------------------------------------------
// k_build: MU[b][i][j] = M_ij ? 0.5*(sc_ij + sc_ji) - s : -1e30, via 64x64
// tile pairs (coalesced transpose through LDS). Also zeroes the per-batch
// sync counters for the persistent kernel (flushed to memory by the implicit
// end-of-kernel release before k_persist starts).
// Grid: BATCH * 36 tile pairs; 256 threads.
// ---------------------------------------------------------------------------
__global__ __launch_bounds__(NTHREADS) void k_build(
    const float* __restrict__ scores, const float* __restrict__ M,
    const float* __restrict__ s_ptr, float* __restrict__ MU,
    unsigned int* __restrict__ counter) {
  __shared__ float Sa[64][65];
  __shared__ float Sb[64][65];
  if (blockIdx.x < BATCH && threadIdx.x == 0) counter[blockIdx.x * CNT_STRIDE] = 0u;
  const int b = blockIdx.x / 36;
  int rem = blockIdx.x % 36;
  int ti = 0;
  while (rem >= 8 - ti) {
    rem -= 8 - ti;
    ti++;
  }
  const int tj = ti + rem;
  const int tid = threadIdx.x;
  const int c = tid & 63;
  const int r0 = tid >> 6;
  const float sval = s_ptr[0];
  const size_t mb = (size_t)b * LDIM * LDIM;
#pragma unroll
  for (int k = 0; k < 16; k++) {
    const int r = 4 * k + r0;
    Sa[r][c] = scores[mb + (size_t)(ti * 64 + r) * LDIM + tj * 64 + c];
    Sb[r][c] = scores[mb + (size_t)(tj * 64 + r) * LDIM + ti * 64 + c];
  }
  __syncthreads();
#pragma unroll
  for (int k = 0; k < 16; k++) {
    const int r = 4 * k + r0;
    const size_t idx_ij = mb + (size_t)(ti * 64 + r) * LDIM + tj * 64 + c;
    const float mij = M[idx_ij];
    const float us = 0.5f * (Sa[r][c] + Sb[c][r]) - sval;
    MU[idx_ij] = (mij != 0.0f) ? us : -1e30f;
    if (ti != tj) {
      const size_t idx_ji = mb + (size_t)(tj * 64 + r) * LDIM + ti * 64 + c;
      const float mji = M[idx_ji];
      const float usj = 0.5f * (Sb[r][c] + Sa[c][r]) - sval;
      MU[idx_ji] = (mji != 0.0f) ? usj : -1e30f;
    }
  }
}

// ---------------------------------------------------------------------------
// k_persist: all 20 steps with A_hat resident on-chip.
// Grid 256 blocks x 1024 threads, 1 block/CU. Block (b = blockIdx&63,
// sb = blockIdx>>6) owns rows [sb*128, sb*128+128) of batch b. The 4 sibling
// blocks of a batch land on the same XCD (64*sb preserves idx%8).
// Per wave (16 waves): 8 rows; rows 0..3 in VGPRs, rows 4..7 in LDS.
// Cross-block exchange per step: 2.5 KB of partials via sc1 relaxed atomics +
// a monotonic per-batch arrival counter. NO fences, NO acquire (see st_agent).
// ---------------------------------------------------------------------------
__global__ __launch_bounds__(PTHREADS, 4) void k_persist(
    const float* __restrict__ scores, const float* __restrict__ MU,
    const float* __restrict__ rho_p, const float* __restrict__ w_ptr,
    const float* __restrict__ alpha_ptr, const float* __restrict__ belt_ptr,
    const float* __restrict__ lra_ptr, const float* __restrict__ lrb_ptr,
    float* __restrict__ rowpart, float* __restrict__ colpart,
    unsigned int* __restrict__ counter, float* __restrict__ Ah) {
  __shared__ float ahL[64][LDIM];    // 128 KB: LDS-resident half of A_hat slab
  __shared__ float stage[8][LDIM];   // 16 KB: cross-wave col-sum staging
  __shared__ float lmsgS[LDIM];      // 2 KB
  __shared__ float LmS[LDIM];        // 2 KB   (total 148 KB <= 160 KB)

  const int tid = threadIdx.x;
  const int lane = tid & 63;
  const int w = tid >> 6;
  const int b = blockIdx.x & (BATCH - 1);
  const int sb = blockIdx.x >> 6;
  const int wrow = sb * 128 + w * 8;
  const int j0 = lane << 2;
  const size_t mb = (size_t)b * LDIM * LDIM;

  const float wv = w_ptr[0];
  const float belt = belt_ptr[0];
  const float lra = lra_ptr[0];
  const float lrb = lrb_ptr[0];
  float at = alpha_ptr[0];  // a_t = alpha * lra^sp, updated iteratively
  float lrbp = 1.0f;        // lrb^(sp-1) for sp>=1

  const size_t RP = (size_t)BATCH * LDIM;      // rowpart buffer stride (parity)
  const size_t CP = (size_t)BATCH * 4 * LDIM;  // colpart buffer stride (parity)
  unsigned int* const cnt = counter + b * CNT_STRIDE;

  f4 ahv[4][2];
  float colacc[8];

  // __syncthreads() drains vmcnt(0) per wave (HIP barrier semantics), so all
  // waves' sc1 partial stores are at MALL before tid0's counter add. RELEASE
  // on the add is formal belt-and-suspenders; its buffer_wbl2 is cheap since
  // the loop makes no plain global stores (no dirty L2 lines). The spin load
  // is RELAXED: sc1 loads always read MALL, no invalidate needed.
#define ARRIVE_WAIT(tgt)                                                       \
  do {                                                                         \
    __syncthreads();                                                           \
    if (tid == 0) {                                                            \
      __hip_atomic_fetch_add(cnt, 1u, __ATOMIC_RELEASE,                        \
                             __HIP_MEMORY_SCOPE_AGENT);                        \
      while (__hip_atomic_load(cnt, __ATOMIC_RELAXED,                          \
                               __HIP_MEMORY_SCOPE_AGENT) < (tgt))              \
        __builtin_amdgcn_s_sleep(8);                                           \
    }                                                                          \
    __syncthreads();                                                           \
  } while (0)

#define COLREDUCE_STORE(dstp)                                                  \
  do {                                                                         \
    if (w < 8) {                                                               \
      f4 sa = {colacc[0], colacc[1], colacc[2], colacc[3]};                    \
      f4 sbv = {colacc[4], colacc[5], colacc[6], colacc[7]};                   \
      *(f4*)&stage[w][j0] = sa;                                                \
      *(f4*)&stage[w][256 + j0] = sbv;                                         \
    }                                                                          \
    __syncthreads();                                                           \
    if (w >= 8) {                                                              \
      f4 sa = *(f4*)&stage[w - 8][j0];                                         \
      f4 sbv = *(f4*)&stage[w - 8][256 + j0];                                  \
      sa[0] += colacc[0]; sa[1] += colacc[1];                                  \
      sa[2] += colacc[2]; sa[3] += colacc[3];                                  \
      sbv[0] += colacc[4]; sbv[1] += colacc[5];                                \
      sbv[2] += colacc[6]; sbv[3] += colacc[7];                                \
      *(f4*)&stage[w - 8][j0] = sa;                                            \
      *(f4*)&stage[w - 8][256 + j0] = sbv;                                     \
    }                                                                          \
    __syncthreads();                                                           \
    if (tid < LDIM) {                                                          \
      float cs = stage[0][tid] + stage[1][tid] + stage[2][tid] +               \
                 stage[3][tid] + stage[4][tid] + stage[5][tid] +               \
                 stage[6][tid] + stage[7][tid];                                \
      st_agent((dstp) + tid, cs);                                              \
    }                                                                          \
  } while (0)

  // ---- P_init: A_hat_0 = scores into regs/LDS; partials of M .* A_hat_0 ----
#pragma unroll
  for (int k = 0; k < 8; k++) colacc[k] = 0.0f;
#pragma unroll
  for (int r = 0; r < 8; r++) {
    const int i = wrow + r;
    const size_t base = mb + (size_t)i * LDIM;
    const f4 s0 = *(const f4*)(scores + base + j0);
    const f4 s1 = *(const f4*)(scores + base + 256 + j0);
    const f4 m0 = *(const f4*)(MU + base + j0);
    const f4 m1 = *(const f4*)(MU + base + 256 + j0);
    if (r < 4) {
      ahv[r][0] = s0;
      ahv[r][1] = s1;
    } else {
      *(f4*)&ahL[(w << 2) + (r - 4)][j0] = s0;
      *(f4*)&ahL[(w << 2) + (r - 4)][256 + j0] = s1;
    }
    float rowc = 0.0f;
#pragma unroll
    for (int k = 0; k < 4; k++) {
      const float c0v = (m0[k] > -1e29f) ? s0[k] : 0.0f;
      const float c1v = (m1[k] > -1e29f) ? s1[k] : 0.0f;
      rowc += c0v + c1v;
      colacc[k] += c0v;
      colacc[4 + k] += c1v;
    }
    const float rsum = wave_reduce_sum(rowc);
    if (lane == 0) st_agent(rowpart + (size_t)b * LDIM + i, rsum);
  }
  COLREDUCE_STORE(colpart + ((size_t)b * 4 + sb) * LDIM);
  ARRIVE_WAIT(4u);

  // ---- 20 steps ----
  for (int sp = 0; sp < NSTEPS; ++sp) {
    const int par = sp & 1;
    // lm phase: identical on all 4 sibling blocks (bit-deterministic).
    if (tid < LDIM) {
      const int i = tid;
      const float rsum = ld_agent(rowpart + (size_t)par * RP + (size_t)b * LDIM + i);
      const float* cb = colpart + (size_t)par * CP + (size_t)b * 4 * LDIM + i;
      const float csum = ld_agent(cb) + ld_agent(cb + LDIM) +
                         ld_agent(cb + 2 * LDIM) + ld_agent(cb + 3 * LDIM);
      const float rd = 0.5f * (rsum + csum) - 1.0f;
      float lm;
      if (sp == 0)
        lm = wv * relu_f(rd);
      else
        lm = LmS[i] + belt * lrbp * relu_f(rd);
      LmS[i] = lm;
      lmsgS[i] = lm * sign_f(rd);
    }
    __syncthreads();

    const f4 lmja = *(const f4*)&lmsgS[j0];
    const f4 lmjb = *(const f4*)&lmsgS[256 + j0];
    const bool last = (sp == NSTEPS - 1);
    const float rat = at;
#pragma unroll
    for (int k = 0; k < 8; k++) colacc[k] = 0.0f;

    // VGPR-resident rows
#pragma unroll
    for (int r = 0; r < 4; r++) {
      const int i = wrow + r;
      const size_t base = mb + (size_t)i * LDIM;
      const float lmi = lmsgS[i];
      const f4 mu0 = *(const f4*)(MU + base + j0);
      const f4 mu1 = *(const f4*)(MU + base + 256 + j0);
      const f4 rh0 = *(const f4*)(rho_p + (size_t)i * LDIM + j0);
      const f4 rh1 = *(const f4*)(rho_p + (size_t)i * LDIM + 256 + j0);
      float rowc = 0.0f;
#pragma unroll
      for (int k = 0; k < 4; k++) {
        const bool ma = mu0[k] > -1e29f;
        const float ga = ma ? (mu0[k] - lmi - lmja[k]) : 0.0f;
        const float ua = ahv[r][0][k] * fmaf(rat, ga, 1.0f);
        const float va = fminf(relu_f(fabsf(ua) - rh0[k] * rat), 1.0f);
        ahv[r][0][k] = va;
        const float ca = ma ? va : 0.0f;
        rowc += ca;
        colacc[k] += ca;
        const bool mbk = mu1[k] > -1e29f;
        const float gb = mbk ? (mu1[k] - lmi - lmjb[k]) : 0.0f;
        const float ub = ahv[r][1][k] * fmaf(rat, gb, 1.0f);
        const float vb = fminf(relu_f(fabsf(ub) - rh1[k] * rat), 1.0f);
        ahv[r][1][k] = vb;
        const float cbv = mbk ? vb : 0.0f;
        rowc += cbv;
        colacc[4 + k] += cbv;
      }
      if (!last) {
        const float rsum = wave_reduce_sum(rowc);
        if (lane == 0)
          st_agent(rowpart + (size_t)(par ^ 1) * RP + (size_t)b * LDIM + i, rsum);
      }
    }
    // LDS-resident rows
#pragma unroll 2
    for (int r = 4; r < 8; r++) {
      const int i = wrow + r;
      const size_t base = mb + (size_t)i * LDIM;
      const int lr = (w << 2) + (r - 4);
      const float lmi = lmsgS[i];
      const f4 mu0 = *(const f4*)(MU + base + j0);
      const f4 mu1 = *(const f4*)(MU + base + 256 + j0);
      const f4 rh0 = *(const f4*)(rho_p + (size_t)i * LDIM + j0);
      const f4 rh1 = *(const f4*)(rho_p + (size_t)i * LDIM + 256 + j0);
      f4 a0 = *(const f4*)&ahL[lr][j0];
      f4 a1 = *(const f4*)&ahL[lr][256 + j0];
      float rowc = 0.0f;
#pragma unroll
      for (int k = 0; k < 4; k++) {
        const bool ma = mu0[k] > -1e29f;
        const float ga = ma ? (mu0[k] - lmi - lmja[k]) : 0.0f;
        const float ua = a0[k] * fmaf(rat, ga, 1.0f);
        const float va = fminf(relu_f(fabsf(ua) - rh0[k] * rat), 1.0f);
        a0[k] = va;
        const float ca = ma ? va : 0.0f;
        rowc += ca;
        colacc[k] += ca;
        const bool mbk = mu1[k] > -1e29f;
        const float gb = mbk ? (mu1[k] - lmi - lmjb[k]) : 0.0f;
        const float ub = a1[k] * fmaf(rat, gb, 1.0f);
        const float vb = fminf(relu_f(fabsf(ub) - rh1[k] * rat), 1.0f);
        a1[k] = vb;
        const float cbv = mbk ? vb : 0.0f;
        rowc += cbv;
        colacc[4 + k] += cbv;
      }
      *(f4*)&ahL[lr][j0] = a0;
      *(f4*)&ahL[lr][256 + j0] = a1;
      if (!last) {
        const float rsum = wave_reduce_sum(rowc);
        if (lane == 0)
          st_agent(rowpart + (size_t)(par ^ 1) * RP + (size_t)b * LDIM + i, rsum);
      }
    }
    if (!last) {
      COLREDUCE_STORE(colpart + (size_t)(par ^ 1) * CP + ((size_t)b * 4 + sb) * LDIM);
      ARRIVE_WAIT(4u * (unsigned)(sp + 2));
    }
    at *= lra;
    if (sp > 0) lrbp *= lrb;
  }

  // ---- write A_hat_20 out (k_final symmetrizes in place) ----
#pragma unroll
  for (int r = 0; r < 4; r++) {
    const size_t base = mb + (size_t)(wrow + r) * LDIM;
    *(f4*)(Ah + base + j0) = ahv[r][0];
    *(f4*)(Ah + base + 256 + j0) = ahv[r][1];
  }
#pragma unroll
  for (int r = 4; r < 8; r++) {
    const size_t base = mb + (size_t)(wrow + r) * LDIM;
    const int lr = (w << 2) + (r - 4);
    *(f4*)(Ah + base + j0) = *(const f4*)&ahL[lr][j0];
    *(f4*)(Ah + base + 256 + j0) = *(const f4*)&ahL[lr][256 + j0];
  }
#undef ARRIVE_WAIT
#undef COLREDUCE_STORE
}

// ---------------------------------------------------------------------------
// K_final: in-place A = 0.5*(Ah + Ah^T) .* M over tile pairs (64x64 tiles).
// ---------------------------------------------------------------------------
__global__ __launch_bounds__(NTHREADS) void k_final(float* __restrict__ Ah,
                                                    const float* __restrict__ M) {
  __shared__ float At[64][65];
  __shared__ float Bt[64][65];
  const int b = blockIdx.x / 36;
  int rem = blockIdx.x % 36;
  int ti = 0;
  while (rem >= 8 - ti) {
    rem -= 8 - ti;
    ti++;
  }
  const int tj = ti + rem;
  const int tid = threadIdx.x;
  const int c = tid & 63;
  const int r0 = tid >> 6;
  const size_t mb = (size_t)b * LDIM * LDIM;

#pragma unroll
  for (int k = 0; k < 16; k++) {
    const int r = 4 * k + r0;
    At[r][c] = Ah[mb + (size_t)(ti * 64 + r) * LDIM + tj * 64 + c];
    Bt[r][c] = Ah[mb + (size_t)(tj * 64 + r) * LDIM + ti * 64 + c];
  }
  __syncthreads();
#pragma unroll
  for (int k = 0; k < 16; k++) {
    const int r = 4 * k + r0;
    const size_t idx_ij = mb + (size_t)(ti * 64 + r) * LDIM + tj * 64 + c;
    const float mij = M[idx_ij];
    Ah[idx_ij] = 0.5f * (At[r][c] + Bt[c][r]) * mij;
    if (ti != tj) {
      const size_t idx_ji = mb + (size_t)(tj * 64 + r) * LDIM + ti * 64 + c;
      const float mji = M[idx_ji];
      Ah[idx_ji] = 0.5f * (Bt[r][c] + At[c][r]) * mji;
    }
  }
}

// ---------------------------------------------------------------------------
extern "C" void kernel_launch(void* const* d_in, const int* in_sizes, int n_in,
                              void* d_out, int out_size, void* d_ws,
                              size_t ws_size, hipStream_t stream) {
  const float* scores = (const float*)d_in[0];
  const float* M = (const float*)d_in[1];
  const float* s_p = (const float*)d_in[2];
  const float* w_p = (const float*)d_in[3];
  const float* rho = (const float*)d_in[4];
  const float* alpha_p = (const float*)d_in[5];
  const float* belt_p = (const float*)d_in[6];
  const float* lra_p = (const float*)d_in[7];
  const float* lrb_p = (const float*)d_in[8];
  float* Ah = (float*)d_out;

  char* ws = (char*)d_ws;
  size_t off = 0;
  auto walloc = [&](size_t bytes) -> void* {
    void* p = (void*)(ws + off);
    off += (bytes + 255) & ~(size_t)255;
    return p;
  };
  const size_t NEL = (size_t)BATCH * LDIM * LDIM;
  float* MU = (float*)walloc(NEL * 4);                              // 64 MB
  float* rowpart = (float*)walloc((size_t)2 * BATCH * LDIM * 4);    // 256 KB
  float* colpart = (float*)walloc((size_t)2 * BATCH * 4 * LDIM * 4);// 1 MB
  unsigned int* cnt = (unsigned int*)walloc(BATCH * CNT_STRIDE * 4);// 4 KB
  (void)in_sizes;
  (void)n_in;
  (void)out_size;
  (void)ws_size;

  k_build<<<dim3(BATCH * 36), dim3(NTHREADS), 0, stream>>>(scores, M, s_p, MU,
                                                           cnt);

  void* args[] = {(void*)&scores, (void*)&MU,      (void*)&rho,
                  (void*)&w_p,    (void*)&alpha_p, (void*)&belt_p,
                  (void*)&lra_p,  (void*)&lrb_p,   (void*)&rowpart,
                  (void*)&colpart, (void*)&cnt,    (void*)&Ah};
  hipError_t cerr = hipLaunchCooperativeKernel(
      (const void*)k_persist, dim3(BATCH * 4), dim3(PTHREADS), args, 0, stream);
  if (cerr != hipSuccess) {
    // Fallback: plain launch. 256 blocks at 1 block/CU on a 256-CU chip are
    // trivially co-resident; the per-batch counter sync is unchanged.
    k_persist<<<dim3(BATCH * 4), dim3(PTHREADS), 0, stream>>>(
        scores, MU, rho, w_p, alpha_p, belt_p, lra_p, lrb_p, rowpart, colpart,
        cnt, Ah);
  }

  k_final<<<dim3(BATCH * 36), dim3(NTHREADS), 0, stream>>>(Ah, M);
}